// Round 5
// baseline (176.681 us; speedup 1.0000x reference)
//
#include <hip/hip_runtime.h>
#include <hip/hip_bf16.h>
#include <cstdint>

typedef __bf16 bf16;
typedef bf16 bf16x8 __attribute__((ext_vector_type(8)));
typedef bf16 bf16x4 __attribute__((ext_vector_type(4)));
typedef float f32x4 __attribute__((ext_vector_type(4)));

#define MFMA16(a, b, c) __builtin_amdgcn_mfma_f32_16x16x32_bf16(a, b, c, 0, 0, 0)

struct rawF { f32x4 a, b; };
__device__ inline rawF ldr(const float* p) {
  rawF r; r.a = *(const f32x4*)p; r.b = *(const f32x4*)(p + 4); return r;
}
__device__ inline bf16x8 ldr(const bf16* p) { return *(const bf16x8*)p; }
__device__ inline bf16x8 cv(const rawF& r) {
  bf16x8 o;
#pragma unroll
  for (int i = 0; i < 4; ++i) { o[i] = (bf16)r.a[i]; o[i + 4] = (bf16)r.b[i]; }
  return o;
}
__device__ inline bf16x8 cv(const bf16x8& r) { return r; }
__device__ inline void stC(bf16* C, size_t i, float v) { C[i] = (bf16)v; }
__device__ inline void stC(float* C, size_t i, float v) { C[i] = v; }

// async global->LDS, 16B per lane (m97 recipe)
__device__ inline void gl16(const bf16* g, bf16* l) {
  __builtin_amdgcn_global_load_lds(
      (const __attribute__((address_space(1))) void*)g,
      (__attribute__((address_space(3))) void*)l, 16, 0, 0);
}

// Tiled operand layout: matrix [R][1024] split into 128x32 tiles (8KB).
// Within a tile, the 16B unit for (row, kq) sits at element offset
//   ((row>>6)&1)<<11 | ((row>>4)&3)<<9 | kq<<7 | ((row&15)^kq)<<3
// so a LINEAR wave-order copy into LDS reproduces the fragment-major image
// proven conflict-free in rounds 2-4.
__device__ inline size_t tile_el(int rowg, int colg) {
  int kq = (colg >> 3) & 3;
  int s = (rowg & 15) ^ kq;
  return ((size_t)(rowg >> 7) * 32 + (colg >> 5)) * 4096 +
         (((rowg >> 6) & 1) << 11) + (((rowg >> 4) & 3) << 9) + (kq << 7) +
         (s << 3) + (colg & 7);
}

// ---- prep (row-major variant, fallback path): W fp32 [K][N] -> W^T bf16 [N][K]
__global__ __launch_bounds__(256) void prep_wt(const float* __restrict__ W0,
                                               const float* __restrict__ W1,
                                               const float* __restrict__ W2,
                                               const float* __restrict__ W3,
                                               bf16* __restrict__ Wt, int n) {
  const float* Ws[4] = {W0, W1, W2, W3};
  const float* W = Ws[blockIdx.z];
  bf16* out = Wt + (size_t)blockIdx.z * n * n;
  __shared__ bf16 t[32][33];
  int bx = blockIdx.x * 32, by = blockIdx.y * 32;
  int tx = threadIdx.x & 31, ty = threadIdx.x >> 5;
#pragma unroll
  for (int i = 0; i < 32; i += 8)
    t[ty + i][tx] = (bf16)W[(size_t)(by + ty + i) * n + bx + tx];
  __syncthreads();
#pragma unroll
  for (int i = 0; i < 32; i += 8)
    out[(size_t)(bx + ty + i) * n + by + tx] = t[tx][ty + i];
}

// ---- prep (tiled variant): W fp32 [K][N] -> W^T bf16 in tiled layout ----
__global__ __launch_bounds__(256) void prep_wt_t(const float* __restrict__ W0,
                                                 const float* __restrict__ W1,
                                                 const float* __restrict__ W2,
                                                 const float* __restrict__ W3,
                                                 bf16* __restrict__ Wt, int n) {
  const float* Ws[4] = {W0, W1, W2, W3};
  const float* W = Ws[blockIdx.z];
  bf16* out = Wt + (size_t)blockIdx.z * n * n;
  __shared__ bf16 t[32][33];
  int bx = blockIdx.x * 32, by = blockIdx.y * 32;
  int tx = threadIdx.x & 31, ty = threadIdx.x >> 5;
#pragma unroll
  for (int i = 0; i < 32; i += 8)
    t[ty + i][tx] = (bf16)W[(size_t)(by + ty + i) * n + bx + tx];
  __syncthreads();
#pragma unroll
  for (int i = 0; i < 32; i += 8) {
    int ng = bx + ty + i, kg = by + tx;  // W^T[ng][kg]
    out[tile_el(ng, kg)] = t[tx][ty + i];
  }
}

// ---- xcvt: x fp32 [4096][1024] -> bf16 tiled ----
__global__ __launch_bounds__(256) void xcvt(const float* __restrict__ x, bf16* __restrict__ Xt) {
  int rbk = blockIdx.x, ks = blockIdx.y, t = threadIdx.x;
  int row = t >> 1, half = t & 1;
  const float* src = x + (size_t)(rbk * 128 + row) * 1024 + ks * 32 + half * 16;
  f32x4 v0 = *(const f32x4*)src;
  f32x4 v1 = *(const f32x4*)(src + 4);
  f32x4 v2 = *(const f32x4*)(src + 8);
  f32x4 v3 = *(const f32x4*)(src + 12);
  bf16* tile = Xt + ((size_t)rbk * 32 + ks) * 4096;
  int rb = (row >> 6) & 1, ii = (row >> 4) & 3;
#pragma unroll
  for (int u = 0; u < 2; ++u) {
    int kq = half * 2 + u;
    int s = (row & 15) ^ kq;
    const f32x4& a = u ? v2 : v0;
    const f32x4& b = u ? v3 : v1;
    bf16x8 o;
#pragma unroll
    for (int j = 0; j < 4; ++j) { o[j] = (bf16)a[j]; o[4 + j] = (bf16)b[j]; }
    *(bf16x8*)&tile[(rb << 11) | (ii << 9) | (kq << 7) | (s << 3)] = o;
  }
}

// ---- transpose V bf16 [b*s][D] -> Vt [bh][hd][2048] ----
__global__ __launch_bounds__(256) void vtrans(const bf16* __restrict__ V, bf16* __restrict__ Vt) {
  constexpr int Sn = 2048, Dn = 1024;
  __shared__ bf16 L[64 * 66];
  int s0 = blockIdx.x * 64, bh = blockIdx.y;
  int b = bh >> 4, h = bh & 15;
  int t = threadIdx.x;
  int r = t >> 3, c8 = (t & 7) * 8;
#pragma unroll
  for (int half = 0; half < 2; ++half) {
    int rr = r + half * 32;
    bf16x8 v = *(const bf16x8*)&V[(size_t)(b * Sn + s0 + rr) * Dn + h * 64 + c8];
#pragma unroll
    for (int j = 0; j < 8; ++j) L[(c8 + j) * 66 + rr] = v[j];
  }
  __syncthreads();
  int hd = t >> 3;
#pragma unroll
  for (int half = 0; half < 2; ++half) {
    int hh = hd + half * 32;
    bf16x8 o;
#pragma unroll
    for (int j = 0; j < 8; ++j) o[j] = L[hh * 66 + c8 + j];
    *(bf16x8*)&Vt[(size_t)bh * 64 * Sn + (size_t)hh * Sn + s0 + c8] = o;
  }
}

// ---- gemmT: C[M,1024] = At @ Bt, both pre-tiled; global_load_lds staging,
// linear LDS = fragment-major image, ONE barrier per K-step, no VALU repack.
template <typename TC>
__global__ __launch_bounds__(256) void gemmT(const bf16* __restrict__ At,
                                             const bf16* __restrict__ B0,
                                             const bf16* __restrict__ B1,
                                             const bf16* __restrict__ B2,
                                             TC* __restrict__ C0, TC* __restrict__ C1,
                                             TC* __restrict__ C2, int nsteps, int nblk) {
  __shared__ bf16 As[2][4096];
  __shared__ bf16 Bs[2][4096];
  int tid = threadIdx.x, wave = tid >> 6, lane = tid & 63;
  int la = lane & 15, quad = lane >> 4;
  int by = blockIdx.y, sel = by / nblk, nb = by - sel * nblk;
  const bf16* Bt = sel == 0 ? B0 : (sel == 1 ? B1 : B2);
  TC* C = sel == 0 ? C0 : (sel == 1 ? C1 : C2);
  const bf16* Atb = At + (size_t)blockIdx.x * nsteps * 4096;
  const bf16* Btb = Bt + (size_t)nb * nsteps * 4096;
  int so = wave * 512 + lane * 8;  // linear element offset, chunk 0 (chunk 1: +2048)
  int rdA = (wave >> 1) * 2048 + quad * 128 + ((la ^ quad) * 8);
  int rdB = (wave & 1) * 2048 + quad * 128 + ((la ^ quad) * 8);

  f32x4 zero = {0.f, 0.f, 0.f, 0.f};
  f32x4 acc[4][4];
#pragma unroll
  for (int i = 0; i < 4; ++i)
#pragma unroll
    for (int j = 0; j < 4; ++j) acc[i][j] = zero;

  // prologue: stage tile 0 into buf 0
  {
    const bf16* ga = Atb;
    const bf16* gb = Btb;
    gl16(ga + so, &As[0][so]);
    gl16(ga + so + 2048, &As[0][so + 2048]);
    gl16(gb + so, &Bs[0][so]);
    gl16(gb + so + 2048, &Bs[0][so + 2048]);
  }
  int cur = 0;
  for (int ks = 0; ks < nsteps; ++ks) {
    __syncthreads();  // buf[cur] ready (vmcnt drained); buf[cur^1] free
    if (ks + 1 < nsteps) {
      const bf16* ga = Atb + (size_t)(ks + 1) * 4096;
      const bf16* gb = Btb + (size_t)(ks + 1) * 4096;
      gl16(ga + so, &As[cur ^ 1][so]);
      gl16(ga + so + 2048, &As[cur ^ 1][so + 2048]);
      gl16(gb + so, &Bs[cur ^ 1][so]);
      gl16(gb + so + 2048, &Bs[cur ^ 1][so + 2048]);
    }
    bf16x8 af[4], bfr[4];
#pragma unroll
    for (int i = 0; i < 4; ++i) af[i] = *(const bf16x8*)&As[cur][rdA + i * 512];
#pragma unroll
    for (int j = 0; j < 4; ++j) bfr[j] = *(const bf16x8*)&Bs[cur][rdB + j * 512];
#pragma unroll
    for (int i = 0; i < 4; ++i)
#pragma unroll
      for (int j = 0; j < 4; ++j) acc[i][j] = MFMA16(af[i], bfr[j], acc[i][j]);
    cur ^= 1;
  }
#pragma unroll
  for (int i = 0; i < 4; ++i) {
#pragma unroll
    for (int j = 0; j < 4; ++j) {
      int col = nb * 128 + (wave & 1) * 64 + j * 16 + la;
#pragma unroll
      for (int r = 0; r < 4; ++r) {
        int row = blockIdx.x * 128 + (wave >> 1) * 64 + i * 16 + quad * 4 + r;
        stC(C, (size_t)row * 1024 + col, acc[i][j][r]);
      }
    }
  }
}

// ---- gemm3 (fallback, round-4 proven) ----
template <typename TA, typename TC, bool BT>
__global__ __launch_bounds__(256) void gemm3(const TA* __restrict__ A,
                                             const void* __restrict__ B0p,
                                             const void* __restrict__ B1p,
                                             const void* __restrict__ B2p,
                                             TC* __restrict__ C0, TC* __restrict__ C1,
                                             TC* __restrict__ C2, int M, int N, int K, int nblk) {
  constexpr int LDA = 40;
  __shared__ bf16 As[BT ? 4096 : 5120];
  __shared__ bf16 Bs[4096];
  int tid = threadIdx.x, wave = tid >> 6, lane = tid & 63;
  int la = lane & 15, quad = lane >> 4;
  int wr = (wave >> 1) * 64, wc = (wave & 1) * 64;
  int by = blockIdx.y;
  int sel = by / nblk;
  int n0 = (by - sel * nblk) * 128;
  const void* Bp = sel == 0 ? B0p : (sel == 1 ? B1p : B2p);
  TC* C = sel == 0 ? C0 : (sel == 1 ? C1 : C2);
  const TA* Ab = A + (size_t)blockIdx.x * 128 * K;
  using TB = typename std::conditional<BT, bf16, float>::type;
  const TB* Bm = (const TB*)Bp;

  int ar[2], ac[2], br[2], bc[2], swz[2];
  int sq = tid & 3;
#pragma unroll
  for (int p = 0; p < 2; ++p) {
    int li = (tid + p * 256) * 8;
    ar[p] = li >> 5; ac[p] = li & 31;
    if (BT) { br[p] = li >> 5; bc[p] = li & 31; }
    else    { br[p] = li >> 7; bc[p] = li & 127; }
    int row = ar[p];
    swz[p] = ((row >> 6) << 12) | (((row >> 4) & 3) << 10) | (sq << 8) |
             ((((row & 15) ^ sq)) << 4);
  }
  int rdA = (wave >> 1) * 4096 + quad * 256 + ((la ^ quad) << 4);
  int rdB = (wave & 1) * 4096 + quad * 256 + ((la ^ quad) << 4);

  f32x4 zero = {0.f, 0.f, 0.f, 0.f};
  f32x4 acc[4][4];
#pragma unroll
  for (int i = 0; i < 4; ++i)
#pragma unroll
    for (int j = 0; j < 4; ++j) acc[i][j] = zero;

  decltype(ldr((const TA*)nullptr)) pa[2];
  decltype(ldr((const TB*)nullptr)) pb[2];
#pragma unroll
  for (int p = 0; p < 2; ++p) {
    pa[p] = ldr(&Ab[(size_t)ar[p] * K + ac[p]]);
    if (BT) pb[p] = ldr(&Bm[(size_t)(n0 + br[p]) * K + bc[p]]);
    else    pb[p] = ldr(&Bm[(size_t)br[p] * N + n0 + bc[p]]);
  }

  for (int k0 = 0; k0 < K; k0 += 32) {
#pragma unroll
    for (int p = 0; p < 2; ++p) {
      if constexpr (BT) {
        *(bf16x8*)((char*)As + swz[p]) = cv(pa[p]);
        *(bf16x8*)((char*)Bs + swz[p]) = cv(pb[p]);
      } else {
        *(bf16x8*)&As[ar[p] * LDA + ac[p]] = cv(pa[p]);
        bf16x8 v = cv(pb[p]);
        int kx = br[p] ^ (((bc[p] >> 3) & 3) << 3);
#pragma unroll
        for (int j = 0; j < 8; ++j) Bs[(bc[p] + j) * 32 + kx] = v[j];
      }
    }
    __syncthreads();
    int k1 = k0 + 32;
    if (k1 < K) {
#pragma unroll
      for (int p = 0; p < 2; ++p) {
        pa[p] = ldr(&Ab[(size_t)ar[p] * K + k1 + ac[p]]);
        if (BT) pb[p] = ldr(&Bm[(size_t)(n0 + br[p]) * K + k1 + bc[p]]);
        else    pb[p] = ldr(&Bm[(size_t)(k1 + br[p]) * N + n0 + bc[p]]);
      }
    }
    bf16x8 af[4], bfr[4];
#pragma unroll
    for (int i = 0; i < 4; ++i) {
      if constexpr (BT)
        af[i] = *(const bf16x8*)((const char*)As + rdA + i * 1024);
      else
        af[i] = *(const bf16x8*)&As[(wr + i * 16 + la) * LDA + quad * 8];
    }
#pragma unroll
    for (int j = 0; j < 4; ++j) {
      if constexpr (BT) {
        bfr[j] = *(const bf16x8*)((const char*)Bs + rdB + j * 1024);
      } else {
        int nr = wc + j * 16 + la;
        bfr[j] = *(const bf16x8*)&Bs[nr * 32 + ((quad * 8) ^ (((nr >> 3) & 3) << 3))];
      }
    }
#pragma unroll
    for (int i = 0; i < 4; ++i)
#pragma unroll
      for (int j = 0; j < 4; ++j) acc[i][j] = MFMA16(af[i], bfr[j], acc[i][j]);
    __syncthreads();
  }
#pragma unroll
  for (int i = 0; i < 4; ++i) {
#pragma unroll
    for (int j = 0; j < 4; ++j) {
      int col = n0 + wc + j * 16 + la;
#pragma unroll
      for (int r = 0; r < 4; ++r) {
        int row = blockIdx.x * 128 + wr + i * 16 + quad * 4 + r;
        stC(C, (size_t)row * N + col, acc[i][j][r]);
      }
    }
  }
}

// ---- flash attention (round-3 proven structure); OT: write O tiled into Ot ----
template <bool OT>
__global__ __launch_bounds__(256) void flash_attn(const bf16* __restrict__ Q,
                                                  const bf16* __restrict__ Kg,
                                                  const bf16* __restrict__ Vtg,
                                                  bf16* __restrict__ O,
                                                  bf16* __restrict__ Ot) {
  constexpr int D = 1024, S = 2048;
  const float MASK = -3.0e4f;
  const float SCL2 = 0.18033688011112042f;  // log2(e)/sqrt(64)
  __shared__ bf16 Ks[4096];
  __shared__ bf16 Vs[4096];
  __shared__ bf16 Ps[4096];

  int n = blockIdx.x;
  int bh = n & 31;
  int j5 = n >> 5;
  int j = j5 & 15;
  int qt = (j5 & 16) ? j : 31 - j;
  int b = bh >> 4, h = bh & 15;
  int tid = threadIdx.x, wave = tid >> 6, lane = tid & 63;
  int la = lane & 15, quad = lane >> 4;
  const size_t base = (size_t)b * S * D + (size_t)h * 64;
  const bf16* Qg = Q + base;
  const bf16* Kb = Kg + base;
  const bf16* Vb = Vtg + (size_t)bh * 64 * S;
  int r0 = tid >> 3, c0 = (tid & 7) * 8;

  int quads = (tid & 7) & 3, kcs = (tid & 7) >> 2;
  int st0 = (r0 >> 4) * 1024 + kcs * 512 + quads * 128 +
            (((r0 & 15) ^ quads ^ (kcs << 2)) * 8);
  int kvrd0 = quad * 128 + ((la ^ quad) * 8);
  int kvrd1 = 512 + quad * 128 + ((la ^ quad ^ 4) * 8);
  int prd0 = wave * 1024 + quad * 128 + ((la ^ ((quad & 1) << 2)) * 8);
  int prd1 = prd0 + 512;
  int pwb = wave * 1024 + (quad >> 1) * 128 +
            ((la ^ ((quad >> 1) << 2)) * 8) + (quad & 1) * 4;

  f32x4 zero = {0.f, 0.f, 0.f, 0.f};
  int q0 = qt * 64;
  int ntiles = qt + 1;

  bf16x8 aq[2];
  {
    int qrow = q0 + wave * 16 + la;
#pragma unroll
    for (int kc = 0; kc < 2; ++kc) {
      bf16x8 t = *(const bf16x8*)&Qg[(size_t)qrow * D + kc * 32 + quad * 8];
#pragma unroll
      for (int i = 0; i < 8; ++i) t[i] = (bf16)((float)t[i] * SCL2);
      aq[kc] = t;
    }
  }

  f32x4 o[4];
#pragma unroll
  for (int nt = 0; nt < 4; ++nt) o[nt] = zero;
  float m_l = MASK, l_l = 0.f;

  bf16x8 kr0 = *(const bf16x8*)&Kb[(size_t)r0 * D + c0];
  bf16x8 kr1 = *(const bf16x8*)&Kb[(size_t)(r0 + 32) * D + c0];
  bf16x8 vr0 = *(const bf16x8*)&Vb[(size_t)r0 * S + c0];
  bf16x8 vr1 = *(const bf16x8*)&Vb[(size_t)(r0 + 32) * S + c0];

  for (int t = 0; t < ntiles; ++t) {
    *(bf16x8*)&Ks[st0] = kr0;
    *(bf16x8*)&Ks[st0 + 2048] = kr1;
    *(bf16x8*)&Vs[st0] = vr0;
    *(bf16x8*)&Vs[st0 + 2048] = vr1;
    __syncthreads();
    if (t + 1 < ntiles) {
      int kb2 = (t + 1) * 64;
      kr0 = *(const bf16x8*)&Kb[(size_t)(kb2 + r0) * D + c0];
      kr1 = *(const bf16x8*)&Kb[(size_t)(kb2 + r0 + 32) * D + c0];
      vr0 = *(const bf16x8*)&Vb[(size_t)r0 * S + kb2 + c0];
      vr1 = *(const bf16x8*)&Vb[(size_t)(r0 + 32) * S + kb2 + c0];
    }

    f32x4 s[4];
    __builtin_amdgcn_s_setprio(1);
#pragma unroll
    for (int nt = 0; nt < 4; ++nt) {
      bf16x8 k0f = *(const bf16x8*)&Ks[nt * 1024 + kvrd0];
      bf16x8 k1f = *(const bf16x8*)&Ks[nt * 1024 + kvrd1];
      f32x4 z = zero;
      z = MFMA16(k0f, aq[0], z);
      z = MFMA16(k1f, aq[1], z);
      s[nt] = z;
    }
    __builtin_amdgcn_s_setprio(0);

    if (t == qt) {
      int qa = q0 + wave * 16 + la;
      int kb = t * 64;
#pragma unroll
      for (int nt = 0; nt < 4; ++nt)
#pragma unroll
        for (int r = 0; r < 4; ++r) {
          int ka = kb + nt * 16 + quad * 4 + r;
          s[nt][r] = (ka > qa) ? MASK : s[nt][r];
        }
    }

    float mx;
    {
      float u0 = fmaxf(fmaxf(s[0][0], s[0][1]), fmaxf(s[0][2], s[0][3]));
      float u1 = fmaxf(fmaxf(s[1][0], s[1][1]), fmaxf(s[1][2], s[1][3]));
      float u2 = fmaxf(fmaxf(s[2][0], s[2][1]), fmaxf(s[2][2], s[2][3]));
      float u3 = fmaxf(fmaxf(s[3][0], s[3][1]), fmaxf(s[3][2], s[3][3]));
      mx = fmaxf(fmaxf(u0, u1), fmaxf(u2, u3));
    }
    mx = fmaxf(mx, m_l);
    mx = fmaxf(mx, __shfl_xor(mx, 16, 64));
    mx = fmaxf(mx, __shfl_xor(mx, 32, 64));

    if (!__all(mx - m_l <= 8.0f)) {
      float alpha = __builtin_amdgcn_exp2f(m_l - mx);
      m_l = mx;
      l_l *= alpha;
      float ab[4];
#pragma unroll
      for (int r = 0; r < 4; ++r) ab[r] = __shfl(alpha, quad * 4 + r, 64);
#pragma unroll
      for (int nt = 0; nt < 4; ++nt)
#pragma unroll
        for (int r = 0; r < 4; ++r) o[nt][r] *= ab[r];
    }

    float rs = 0.f;
#pragma unroll
    for (int nt = 0; nt < 4; ++nt) {
      float p0 = __builtin_amdgcn_exp2f(s[nt][0] - m_l);
      float p1 = __builtin_amdgcn_exp2f(s[nt][1] - m_l);
      float p2 = __builtin_amdgcn_exp2f(s[nt][2] - m_l);
      float p3 = __builtin_amdgcn_exp2f(s[nt][3] - m_l);
      s[nt][0] = p0; s[nt][1] = p1; s[nt][2] = p2; s[nt][3] = p3;
      rs += (p0 + p1) + (p2 + p3);
    }
    rs += __shfl_xor(rs, 16, 64);
    rs += __shfl_xor(rs, 32, 64);
    l_l += rs;

#pragma unroll
    for (int nt = 0; nt < 4; ++nt) {
      bf16x4 pk;
#pragma unroll
      for (int r = 0; r < 4; ++r) pk[r] = (bf16)s[nt][r];
      *(bf16x4*)&Ps[pwb + nt * 256] = pk;
    }

    __builtin_amdgcn_s_setprio(1);
    {
      bf16x8 ap0 = *(const bf16x8*)&Ps[prd0];
#pragma unroll
      for (int nt = 0; nt < 4; ++nt) {
        bf16x8 bv = *(const bf16x8*)&Vs[nt * 1024 + kvrd0];
        o[nt] = MFMA16(ap0, bv, o[nt]);
      }
      bf16x8 ap1 = *(const bf16x8*)&Ps[prd1];
#pragma unroll
      for (int nt = 0; nt < 4; ++nt) {
        bf16x8 bv = *(const bf16x8*)&Vs[nt * 1024 + kvrd1];
        o[nt] = MFMA16(ap1, bv, o[nt]);
      }
    }
    __builtin_amdgcn_s_setprio(0);
    __syncthreads();
  }

  float inv[4];
#pragma unroll
  for (int r = 0; r < 4; ++r) {
    float lv = __shfl(l_l, quad * 4 + r, 64);
    inv[r] = (lv > 1e-30f) ? 1.0f / lv : 0.0f;
  }
#pragma unroll
  for (int nt = 0; nt < 4; ++nt) {
    int hd = nt * 16 + la;
#pragma unroll
    for (int r = 0; r < 4; ++r) {
      int row = q0 + wave * 16 + quad * 4 + r;
      float v = o[nt][r] * inv[r];
      if (OT) {
        int rowg = b * S + row, colg = h * 64 + hd;
        Ot[tile_el(rowg, colg)] = (bf16)v;
      } else {
        O[base + (size_t)row * D + hd] = (bf16)v;
      }
    }
  }
}

extern "C" void kernel_launch(void* const* d_in, const int* in_sizes, int n_in,
                              void* d_out, int out_size, void* d_ws, size_t ws_size,
                              hipStream_t stream) {
  constexpr int B = 2, S = 2048, D = 1024;
  constexpr int M = B * S;
  constexpr size_t WN = (size_t)D * D;
  constexpr size_t XN = (size_t)M * D;

  const float* x = (const float*)d_in[0];
  const float* Wq = (const float*)d_in[1];
  const float* Wk = (const float*)d_in[2];
  const float* Wv = (const float*)d_in[3];
  const float* Wo = (const float*)d_in[4];
  float* out = (float*)d_out;

  if (ws_size < 2 * XN * sizeof(bf16)) return;
  bf16* Qb = (bf16*)d_ws;   // [0,8MB): Q (row-major); fallback: also O
  bf16* Vtg = Qb + XN;      // [8,16MB): V^T [bh][hd][s]
  bf16* Wt = Vtg + XN;      // [16,24MB): 4x W^T bf16 (tiled or row-major)
  bf16* Xt = Wt + 4 * WN;   // [24,32MB): x tiled; reused as O tiled (big_ws only)
  bf16* Kb = (bf16*)d_out;  // d_out[0,8MB): K (scratch until final gemm)
  bf16* Vb = Kb + XN;       // d_out[8,16MB): V (dead after vtrans)
  bool use_bt = ws_size >= (2 * XN + 4 * WN) * sizeof(bf16);
  bool big_ws = ws_size >= (3 * XN + 4 * WN) * sizeof(bf16);

  if (big_ws) {
    // fast path: tiled operands + global_load_lds GEMMs
    prep_wt_t<<<dim3(32, 32, 4), 256, 0, stream>>>(Wq, Wk, Wv, Wo, Wt, D);
    xcvt<<<dim3(32, 32), 256, 0, stream>>>(x, Xt);
    gemmT<bf16><<<dim3(M / 128, 24), 256, 0, stream>>>(Xt, Wt, Wt + WN, Wt + 2 * WN,
                                                       Qb, Kb, Vb, 32, 8);
    vtrans<<<dim3(S / 64, 32), 256, 0, stream>>>(Vb, Vtg);
    flash_attn<true><<<dim3(1024), 256, 0, stream>>>(Qb, Kb, Vtg, nullptr, Xt);
    gemmT<float><<<dim3(M / 128, 8), 256, 0, stream>>>(Xt, Wt + 3 * WN, Wt + 3 * WN,
                                                       Wt + 3 * WN, out, out, out, 32, 8);
    return;
  }

  dim3 gq(M / 128, 24), gf(M / 128, 8);
  if (use_bt) {
    prep_wt<<<dim3(32, 32, 4), 256, 0, stream>>>(Wq, Wk, Wv, Wo, Wt, D);
    gemm3<float, bf16, true><<<gq, 256, 0, stream>>>(x, Wt, Wt + WN, Wt + 2 * WN,
                                                     Qb, Kb, Vb, M, D, D, 8);
  } else {
    gemm3<float, bf16, false><<<gq, 256, 0, stream>>>(x, Wq, Wk, Wv, Qb, Kb, Vb, M, D, D, 8);
  }
  vtrans<<<dim3(S / 64, 32), 256, 0, stream>>>(Vb, Vtg);
  flash_attn<false><<<dim3(1024), 256, 0, stream>>>(Qb, Kb, Vtg, Qb, nullptr);
  if (use_bt) {
    gemm3<bf16, float, true><<<gf, 256, 0, stream>>>(Qb, Wt + 3 * WN, Wt + 3 * WN, Wt + 3 * WN,
                                                     out, out, out, M, D, D, 8);
  } else {
    gemm3<bf16, float, false><<<gf, 256, 0, stream>>>(Qb, Wo, Wo, Wo, out, out, out, M, D, D, 8);
  }
}